// Round 1
// baseline (1237.720 us; speedup 1.0000x reference)
//
#include <hip/hip_runtime.h>
#include <hip/hip_bf16.h>

#define HID 1024
#define HEADS 16
#define FEAT 16
#define HD 64
#define T_LEN 1024
#define NFEAT 136   // 16 diag + 120 off-diag

// ---------------------------------------------------------------------------
// Generic tiled f32 GEMM:  C[M,N] = A[M,K] @ W[N,K]^T   (all row-major)
// 64x64 tile, 256 threads, 4x4 micro-tile per thread, BK=16.
// M,N,K all multiples of 64 here, so no bounds checks.
// ---------------------------------------------------------------------------
__global__ __launch_bounds__(256) void gemm_abt(const float* __restrict__ A,
                                                const float* __restrict__ W,
                                                float* __restrict__ C,
                                                int M, int N, int K) {
    __shared__ float As[16][68];  // [k][m], stride 68 to dodge bank conflicts
    __shared__ float Ws[16][68];  // [k][n]

    const int bm = blockIdx.y * 64;
    const int bn = blockIdx.x * 64;
    const int tid = threadIdx.x;
    const int tx = tid & 15;        // 0..15 -> n quad
    const int ty = tid >> 4;        // 0..15 -> m quad
    const int lm = tid >> 2;        // 0..63  row for loading
    const int lk = (tid & 3) << 2;  // 0,4,8,12

    float acc[4][4];
#pragma unroll
    for (int i = 0; i < 4; ++i)
#pragma unroll
        for (int j = 0; j < 4; ++j) acc[i][j] = 0.f;

    for (int k0 = 0; k0 < K; k0 += 16) {
        float4 av = *(const float4*)&A[(size_t)(bm + lm) * K + k0 + lk];
        float4 wv = *(const float4*)&W[(size_t)(bn + lm) * K + k0 + lk];
        As[lk + 0][lm] = av.x; As[lk + 1][lm] = av.y;
        As[lk + 2][lm] = av.z; As[lk + 3][lm] = av.w;
        Ws[lk + 0][lm] = wv.x; Ws[lk + 1][lm] = wv.y;
        Ws[lk + 2][lm] = wv.z; Ws[lk + 3][lm] = wv.w;
        __syncthreads();
#pragma unroll
        for (int kk = 0; kk < 16; ++kk) {
            float4 a4 = *(const float4*)&As[kk][ty << 2];
            float4 b4 = *(const float4*)&Ws[kk][tx << 2];
            float a[4] = {a4.x, a4.y, a4.z, a4.w};
            float b[4] = {b4.x, b4.y, b4.z, b4.w};
#pragma unroll
            for (int i = 0; i < 4; ++i)
#pragma unroll
                for (int j = 0; j < 4; ++j) acc[i][j] += a[i] * b[j];
        }
        __syncthreads();
    }

#pragma unroll
    for (int i = 0; i < 4; ++i) {
        float4 o = make_float4(acc[i][0], acc[i][1], acc[i][2], acc[i][3]);
        *(float4*)&C[(size_t)(bm + (ty << 2) + i) * N + bn + (tx << 2)] = o;
    }
}

// ---------------------------------------------------------------------------
// Feature map: per (head,t) position, LayerNorm(16) + quadratic features(136).
// qk: [T, HEADS*FEAT] (col = h*16+f).  phi: [HEADS][T][136]
// ---------------------------------------------------------------------------
__global__ __launch_bounds__(256) void feat_kernel(const float* __restrict__ qk,
                                                   const float* __restrict__ gamma,
                                                   const float* __restrict__ beta,
                                                   float* __restrict__ phi) {
    int p = blockIdx.x * blockDim.x + threadIdx.x;  // 0..16383
    int h = p >> 10;
    int t = p & 1023;

    float x[16];
    float mu = 0.f;
#pragma unroll
    for (int f = 0; f < 16; ++f) {
        x[f] = qk[(size_t)t * (HEADS * FEAT) + h * FEAT + f];
        mu += x[f];
    }
    mu *= (1.f / 16.f);
    float var = 0.f;
#pragma unroll
    for (int f = 0; f < 16; ++f) {
        float d = x[f] - mu;
        var += d * d;
    }
    var *= (1.f / 16.f);
    float rstd = rsqrtf(var + 1e-5f);

    float xn[16];
#pragma unroll
    for (int f = 0; f < 16; ++f)
        xn[f] = (x[f] - mu) * rstd * gamma[f] + beta[f];

    float* outp = phi + ((size_t)(h << 10) + t) * NFEAT;
    const float c1 = 0.25f;                 // FEAT^-0.5
    const float c2 = 0.35355339059327373f;  // sqrt(2/FEAT)
#pragma unroll
    for (int f = 0; f < 16; ++f) outp[f] = xn[f] * xn[f] * c1;
    int idx = 16;
#pragma unroll
    for (int i = 0; i < 16; ++i)
#pragma unroll
        for (int j = i + 1; j < 16; ++j) outp[idx++] = xn[i] * xn[j] * c2;
}

// ---------------------------------------------------------------------------
// Causal linear-attention recurrence. One block per head, 256 threads.
// Thread (d = tid>>2, g = tid&3) owns S[f,d], z[f] for f in [g*34, g*34+34).
// v: [T, HEADS*HD]  y: [T, HEADS*HD]
// ---------------------------------------------------------------------------
__global__ __launch_bounds__(256) void attn_kernel(const float* __restrict__ phi_q,
                                                   const float* __restrict__ phi_k,
                                                   const float* __restrict__ v,
                                                   float* __restrict__ y) {
    const int h = blockIdx.x;
    const int tid = threadIdx.x;
    const int d = tid >> 2;   // 0..63
    const int g = tid & 3;    // 0..3
    const int f0 = g * 34;

    __shared__ float s_pq[NFEAT];
    __shared__ float s_pk[NFEAT];
    __shared__ float s_v[HD];

    float S[34];
    float z[34];
#pragma unroll
    for (int i = 0; i < 34; ++i) { S[i] = 0.f; z[i] = 0.f; }

    const float* pq_base = phi_q + (size_t)(h << 10) * NFEAT;
    const float* pk_base = phi_k + (size_t)(h << 10) * NFEAT;

    for (int t = 0; t < T_LEN; ++t) {
        if (tid < NFEAT) {
            s_pq[tid] = pq_base[(size_t)t * NFEAT + tid];
            s_pk[tid] = pk_base[(size_t)t * NFEAT + tid];
        } else if (tid < NFEAT + HD) {
            s_v[tid - NFEAT] = v[(size_t)t * (HEADS * HD) + (h << 6) + (tid - NFEAT)];
        }
        __syncthreads();

        float vd = s_v[d];
        float num = 0.f, den = 0.f;
#pragma unroll
        for (int i = 0; i < 34; ++i) {
            float pk = s_pk[f0 + i];
            float pq = s_pq[f0 + i];
            S[i] += pk * vd;
            z[i] += pk;
            num += pq * S[i];
            den += pq * z[i];
        }
        num += __shfl_xor(num, 1);
        num += __shfl_xor(num, 2);
        den += __shfl_xor(den, 1);
        den += __shfl_xor(den, 2);

        if (g == 0)
            y[(size_t)t * (HEADS * HD) + (h << 6) + d] = num / (den + 1e-5f);
        __syncthreads();
    }
}

extern "C" void kernel_launch(void* const* d_in, const int* in_sizes, int n_in,
                              void* d_out, int out_size, void* d_ws, size_t ws_size,
                              hipStream_t stream) {
    const float* hs    = (const float*)d_in[0];
    const float* Wq    = (const float*)d_in[1];
    const float* Wk    = (const float*)d_in[2];
    const float* Wv    = (const float*)d_in[3];
    const float* Wo    = (const float*)d_in[4];
    const float* gamma = (const float*)d_in[5];
    const float* beta  = (const float*)d_in[6];
    float* out = (float*)d_out;

    float* ws = (float*)d_ws;
    float* q     = ws;                       // 1024*256
    float* k     = q + 1024 * 256;           // 1024*256
    float* v     = k + 1024 * 256;           // 1024*1024
    float* phi_q = v + 1024 * 1024;          // 16*1024*136
    float* phi_k = phi_q + HEADS * T_LEN * NFEAT;
    float* y     = phi_k + HEADS * T_LEN * NFEAT;  // 1024*1024

    dim3 blk(256);
    // q = hs @ Wq^T : [1024, 256]
    gemm_abt<<<dim3(256 / 64, 1024 / 64), blk, 0, stream>>>(hs, Wq, q, 1024, 256, 1024);
    // k = hs @ Wk^T : [1024, 256]
    gemm_abt<<<dim3(256 / 64, 1024 / 64), blk, 0, stream>>>(hs, Wk, k, 1024, 256, 1024);
    // v = hs @ Wv^T : [1024, 1024]
    gemm_abt<<<dim3(1024 / 64, 1024 / 64), blk, 0, stream>>>(hs, Wv, v, 1024, 1024, 1024);

    feat_kernel<<<64, 256, 0, stream>>>(q, gamma, beta, phi_q);
    feat_kernel<<<64, 256, 0, stream>>>(k, gamma, beta, phi_k);

    attn_kernel<<<HEADS, 256, 0, stream>>>(phi_q, phi_k, v, y);

    // out = y @ Wo^T : [1024, 1024]
    gemm_abt<<<dim3(1024 / 64, 1024 / 64), blk, 0, stream>>>(y, Wo, out, 1024, 1024, 1024);
}

// Round 2
// 274.660 us; speedup vs baseline: 4.5064x; 4.5064x over previous
//
#include <hip/hip_runtime.h>
#include <hip/hip_bf16.h>

#define HID 1024
#define HEADS 16
#define FEAT 16
#define HD 64
#define T_LEN 1024
#define NFEAT 136   // 16 diag + 120 off-diag
#define CL 32       // chunk length
#define NC 32       // chunks per head = T_LEN / CL
#define SSTATE (NFEAT * HD)  // 8704 state entries per head

// ---------------------------------------------------------------------------
// Generic tiled f32 GEMM:  C[M,N] = A[M,K] @ W[N,K]^T   (all row-major)
// 64x64 tile, 256 threads, 4x4 micro-tile per thread, BK=16.
// ---------------------------------------------------------------------------
__global__ __launch_bounds__(256) void gemm_abt(const float* __restrict__ A,
                                                const float* __restrict__ W,
                                                float* __restrict__ C,
                                                int M, int N, int K) {
    __shared__ float As[16][68];
    __shared__ float Ws[16][68];

    const int bm = blockIdx.y * 64;
    const int bn = blockIdx.x * 64;
    const int tid = threadIdx.x;
    const int tx = tid & 15;
    const int ty = tid >> 4;
    const int lm = tid >> 2;
    const int lk = (tid & 3) << 2;

    float acc[4][4];
#pragma unroll
    for (int i = 0; i < 4; ++i)
#pragma unroll
        for (int j = 0; j < 4; ++j) acc[i][j] = 0.f;

    for (int k0 = 0; k0 < K; k0 += 16) {
        float4 av = *(const float4*)&A[(size_t)(bm + lm) * K + k0 + lk];
        float4 wv = *(const float4*)&W[(size_t)(bn + lm) * K + k0 + lk];
        As[lk + 0][lm] = av.x; As[lk + 1][lm] = av.y;
        As[lk + 2][lm] = av.z; As[lk + 3][lm] = av.w;
        Ws[lk + 0][lm] = wv.x; Ws[lk + 1][lm] = wv.y;
        Ws[lk + 2][lm] = wv.z; Ws[lk + 3][lm] = wv.w;
        __syncthreads();
#pragma unroll
        for (int kk = 0; kk < 16; ++kk) {
            float4 a4 = *(const float4*)&As[kk][ty << 2];
            float4 b4 = *(const float4*)&Ws[kk][tx << 2];
            float a[4] = {a4.x, a4.y, a4.z, a4.w};
            float b[4] = {b4.x, b4.y, b4.z, b4.w};
#pragma unroll
            for (int i = 0; i < 4; ++i)
#pragma unroll
                for (int j = 0; j < 4; ++j) acc[i][j] += a[i] * b[j];
        }
        __syncthreads();
    }

#pragma unroll
    for (int i = 0; i < 4; ++i) {
        float4 o = make_float4(acc[i][0], acc[i][1], acc[i][2], acc[i][3]);
        *(float4*)&C[(size_t)(bm + (ty << 2) + i) * N + bn + (tx << 2)] = o;
    }
}

// ---------------------------------------------------------------------------
// Feature map: per (head,t), LayerNorm(16) + quadratic features(136).
// qk: [T, HEADS*FEAT].  phi: [HEADS][T][136]
// ---------------------------------------------------------------------------
__global__ __launch_bounds__(256) void feat_kernel(const float* __restrict__ qk,
                                                   const float* __restrict__ gamma,
                                                   const float* __restrict__ beta,
                                                   float* __restrict__ phi) {
    int p = blockIdx.x * blockDim.x + threadIdx.x;
    int h = p >> 10;
    int t = p & 1023;

    float x[16];
    float mu = 0.f;
#pragma unroll
    for (int f = 0; f < 16; ++f) {
        x[f] = qk[(size_t)t * (HEADS * FEAT) + h * FEAT + f];
        mu += x[f];
    }
    mu *= (1.f / 16.f);
    float var = 0.f;
#pragma unroll
    for (int f = 0; f < 16; ++f) {
        float d = x[f] - mu;
        var += d * d;
    }
    var *= (1.f / 16.f);
    float rstd = rsqrtf(var + 1e-5f);

    float xn[16];
#pragma unroll
    for (int f = 0; f < 16; ++f)
        xn[f] = (x[f] - mu) * rstd * gamma[f] + beta[f];

    float* outp = phi + ((size_t)(h << 10) + t) * NFEAT;
    const float c1 = 0.25f;
    const float c2 = 0.35355339059327373f;
#pragma unroll
    for (int f = 0; f < 16; ++f) outp[f] = xn[f] * xn[f] * c1;
    int idx = 16;
#pragma unroll
    for (int i = 0; i < 16; ++i)
#pragma unroll
        for (int j = i + 1; j < 16; ++j) outp[idx++] = xn[i] * xn[j] * c2;
}

// ---------------------------------------------------------------------------
// Phase 1: per-chunk KV outer-product sums and K-feature sums.
// KV[h][c][f][d] = sum_{t in chunk} phi_k[h][t][f] * v[t][h*64+d]
// Z[h][c][f]    = sum_{t in chunk} phi_k[h][t][f]
// grid (NC, HEADS), 256 threads.
// ---------------------------------------------------------------------------
__global__ __launch_bounds__(256) void chunk_kv(const float* __restrict__ phi_k,
                                                const float* __restrict__ v,
                                                float* __restrict__ KV,
                                                float* __restrict__ Z) {
    const int c = blockIdx.x;
    const int h = blockIdx.y;
    const int tid = threadIdx.x;
    __shared__ float pk_s[CL * NFEAT];  // 4352 floats
    __shared__ float v_s[CL * HD];      // 2048 floats

    const float* pk_g = phi_k + ((size_t)(h * T_LEN + c * CL)) * NFEAT;
    for (int idx = tid; idx < CL * NFEAT; idx += 256) pk_s[idx] = pk_g[idx];
    for (int idx = tid; idx < CL * HD; idx += 256) {
        int t = idx >> 6, d = idx & 63;
        v_s[idx] = v[(size_t)(c * CL + t) * (HEADS * HD) + h * HD + d];
    }
    __syncthreads();

    const int d = tid & 63;
    const int fg = tid >> 6;  // 0..3 -> f in [fg*34, fg*34+34)
    float* kv_out = KV + ((size_t)(h * NC + c)) * SSTATE;
    float* z_out = Z + ((size_t)(h * NC + c)) * NFEAT;
    for (int n = 0; n < 34; ++n) {
        int f = fg * 34 + n;
        float acc = 0.f;
        float zacc = 0.f;
#pragma unroll
        for (int t = 0; t < CL; ++t) {
            float pk = pk_s[t * NFEAT + f];  // broadcast within wave
            acc += pk * v_s[t * HD + d];
            zacc += pk;
        }
        kv_out[f * HD + d] = acc;
        if (d == 0) z_out[f] = zacc;
    }
}

// ---------------------------------------------------------------------------
// Phase 2: in-place exclusive prefix scan over chunks (per head).
// grid (35, HEADS): bx 0..33 -> 256-entry slices of the 8704 KV state,
// bx==34 -> the 136 Z entries. Serial only over the 32 chunks.
// ---------------------------------------------------------------------------
__global__ __launch_bounds__(256) void chunk_scan(float* __restrict__ KV,
                                                  float* __restrict__ Z) {
    const int bx = blockIdx.x;
    const int h = blockIdx.y;
    const int tid = threadIdx.x;
    if (bx < 34) {
        int e = bx * 256 + tid;  // 0..8703
        float run = 0.f;
        float* base = KV + (size_t)h * NC * SSTATE + e;
        for (int c = 0; c < NC; ++c) {
            float val = base[(size_t)c * SSTATE];
            base[(size_t)c * SSTATE] = run;
            run += val;
        }
    } else if (tid < NFEAT) {
        float run = 0.f;
        float* base = Z + (size_t)h * NC * NFEAT + tid;
        for (int c = 0; c < NC; ++c) {
            float val = base[(size_t)c * NFEAT];
            base[(size_t)c * NFEAT] = run;
            run += val;
        }
    }
}

// ---------------------------------------------------------------------------
// Phase 3: per-chunk output.
//   A = causal(phi_q_c @ phi_k_c^T)   (32x32, diag included)
//   num[t][d] = phi_q[t] . KVpref[:,d] + sum_{s<=t} A[t][s] v[s][d]
//   den[t]    = phi_q[t] . Zpref      + sum_{s<=t} A[t][s]
//   y = num / (den + 1e-5)
// grid (NC, HEADS), 256 threads. LDS ~46 KB.
// ---------------------------------------------------------------------------
__global__ __launch_bounds__(256) void chunk_out(const float* __restrict__ phi_q,
                                                 const float* __restrict__ phi_k,
                                                 const float* __restrict__ v,
                                                 const float* __restrict__ KV,
                                                 const float* __restrict__ Z,
                                                 float* __restrict__ y) {
    const int c = blockIdx.x;
    const int h = blockIdx.y;
    const int tid = threadIdx.x;

    __shared__ float pq_s[CL * 137];  // padded stride 137 (bank-conflict-free)
    __shared__ float pk_s[CL * 137];
    __shared__ float A_s[CL * CL];
    __shared__ float v_s[CL * HD];

    const float* pq_g = phi_q + ((size_t)(h * T_LEN + c * CL)) * NFEAT;
    const float* pk_g = phi_k + ((size_t)(h * T_LEN + c * CL)) * NFEAT;
    for (int idx = tid; idx < CL * NFEAT; idx += 256) {
        int t = idx / NFEAT;
        pq_s[idx + t] = pq_g[idx];  // t*137+f == idx+t
        pk_s[idx + t] = pk_g[idx];
    }
    for (int idx = tid; idx < CL * HD; idx += 256) {
        int t = idx >> 6, d = idx & 63;
        v_s[idx] = v[(size_t)(c * CL + t) * (HEADS * HD) + h * HD + d];
    }
    __syncthreads();

    // A[t][s], causal-masked (zero above diagonal so later loops are branch-free)
    for (int e = tid; e < CL * CL; e += 256) {
        int t = e >> 5, s = e & 31;
        float acc = 0.f;
        if (s <= t) {
#pragma unroll 8
            for (int f = 0; f < NFEAT; ++f)
                acc += pq_s[t * 137 + f] * pk_s[s * 137 + f];
        }
        A_s[e] = acc;
    }
    __syncthreads();

    const int d = tid & 63;
    const int tg = tid >> 6;  // owns t = tg*8 + i, i in [0,8)
    const float* kv_pref = KV + ((size_t)(h * NC + c)) * SSTATE;
    const float* z_pref = Z + ((size_t)(h * NC + c)) * NFEAT;

    float num[8], den[8];
#pragma unroll
    for (int i = 0; i < 8; ++i) { num[i] = 0.f; den[i] = 0.f; }

    for (int f = 0; f < NFEAT; ++f) {
        float sp = kv_pref[f * HD + d];  // coalesced across d
        float zp = z_pref[f];
#pragma unroll
        for (int i = 0; i < 8; ++i) {
            float pq = pq_s[(tg * 8 + i) * 137 + f];  // wave-broadcast
            num[i] += pq * sp;
            den[i] += pq * zp;
        }
    }
#pragma unroll
    for (int s = 0; s < CL; ++s) {
        float vv = v_s[s * HD + d];
#pragma unroll
        for (int i = 0; i < 8; ++i) {
            float a = A_s[(tg * 8 + i) * CL + s];  // wave-broadcast; 0 if masked
            num[i] += a * vv;
            den[i] += a;
        }
    }
#pragma unroll
    for (int i = 0; i < 8; ++i) {
        int t = c * CL + tg * 8 + i;
        y[(size_t)t * (HEADS * HD) + h * HD + d] = num[i] / (den[i] + 1e-5f);
    }
}

extern "C" void kernel_launch(void* const* d_in, const int* in_sizes, int n_in,
                              void* d_out, int out_size, void* d_ws, size_t ws_size,
                              hipStream_t stream) {
    const float* hs    = (const float*)d_in[0];
    const float* Wq    = (const float*)d_in[1];
    const float* Wk    = (const float*)d_in[2];
    const float* Wv    = (const float*)d_in[3];
    const float* Wo    = (const float*)d_in[4];
    const float* gamma = (const float*)d_in[5];
    const float* beta  = (const float*)d_in[6];
    float* out = (float*)d_out;

    float* ws = (float*)d_ws;
    float* q     = ws;                                   // 1024*256
    float* k     = q + 1024 * 256;                       // 1024*256
    float* v     = k + 1024 * 256;                       // 1024*1024
    float* phi_q = v + 1024 * 1024;                      // 16*1024*136
    float* phi_k = phi_q + HEADS * T_LEN * NFEAT;        // 16*1024*136
    float* y     = phi_k + HEADS * T_LEN * NFEAT;        // 1024*1024
    float* KV    = y + 1024 * 1024;                      // 16*32*8704
    float* Z     = KV + (size_t)HEADS * NC * SSTATE;     // 16*32*136

    dim3 blk(256);
    gemm_abt<<<dim3(256 / 64, 1024 / 64), blk, 0, stream>>>(hs, Wq, q, 1024, 256, 1024);
    gemm_abt<<<dim3(256 / 64, 1024 / 64), blk, 0, stream>>>(hs, Wk, k, 1024, 256, 1024);
    gemm_abt<<<dim3(1024 / 64, 1024 / 64), blk, 0, stream>>>(hs, Wv, v, 1024, 1024, 1024);

    feat_kernel<<<64, 256, 0, stream>>>(q, gamma, beta, phi_q);
    feat_kernel<<<64, 256, 0, stream>>>(k, gamma, beta, phi_k);

    chunk_kv<<<dim3(NC, HEADS), blk, 0, stream>>>(phi_k, v, KV, Z);
    chunk_scan<<<dim3(35, HEADS), blk, 0, stream>>>(KV, Z);
    chunk_out<<<dim3(NC, HEADS), blk, 0, stream>>>(phi_q, phi_k, v, KV, Z, y);

    gemm_abt<<<dim3(1024 / 64, 1024 / 64), blk, 0, stream>>>(y, Wo, out, 1024, 1024, 1024);
}

// Round 4
// 187.204 us; speedup vs baseline: 6.6116x; 1.4672x over previous
//
#include <hip/hip_runtime.h>
#include <hip/hip_bf16.h>

#define HID 1024
#define HEADS 16
#define FEAT 16
#define HD 64
#define T_LEN 1024
#define NFEAT 136   // 16 diag + 120 off-diag
#define CL 32       // chunk length
#define NC 32       // chunks per head
#define SSTATE (NFEAT * HD)  // 8704
#define QKV_N 1536  // 256 q + 256 k + 1024 v
#define K3 3072     // 3-segment split-K

typedef __attribute__((ext_vector_type(8))) short short8;
typedef __attribute__((ext_vector_type(4))) float f32x4;

// ---------------------------------------------------------------------------
// f32 <-> bf16 helpers
// ---------------------------------------------------------------------------
__device__ __forceinline__ unsigned short f2bf(float f) {
    union { float f; unsigned int u; } x;
    x.f = f;
    unsigned int u = x.u;
    unsigned int r = u + 0x7fffu + ((u >> 16) & 1u);
    return (unsigned short)(r >> 16);
}
__device__ __forceinline__ float bf2f(unsigned short s) {
    union { unsigned int u; float f; } x;
    x.u = ((unsigned int)s) << 16;
    return x.f;
}

// plain f32 -> bf16, 8 elems/thread
__global__ __launch_bounds__(256) void cvt_bf16(const float* __restrict__ in,
                                                unsigned short* __restrict__ out,
                                                int n) {
    int i = (blockIdx.x * 256 + threadIdx.x) * 8;
    if (i >= n) return;
    float4 a = *(const float4*)&in[i];
    float4 b = *(const float4*)&in[i + 4];
    union { unsigned short s[8]; short8 v; } o;
    o.s[0] = f2bf(a.x); o.s[1] = f2bf(a.y); o.s[2] = f2bf(a.z); o.s[3] = f2bf(a.w);
    o.s[4] = f2bf(b.x); o.s[5] = f2bf(b.y); o.s[6] = f2bf(b.z); o.s[7] = f2bf(b.w);
    *(short8*)&out[i] = o.v;
}

// split f32 [rows][1024] -> bf16 [rows][3072].
// MODE_A: segments [hi | lo | hi].  MODE_B: segments [hi | hi | lo].
template <int MODE_A>
__global__ __launch_bounds__(256) void cvt_split(const float* __restrict__ in,
                                                 unsigned short* __restrict__ out,
                                                 int n) {
    int i = (blockIdx.x * 256 + threadIdx.x) * 8;
    if (i >= n) return;
    int row = i >> 10;
    int k = i & 1023;
    float4 a = *(const float4*)&in[i];
    float4 b = *(const float4*)&in[i + 4];
    float x[8] = {a.x, a.y, a.z, a.w, b.x, b.y, b.z, b.w};
    union { unsigned short s[8]; short8 v; } hi, lo;
#pragma unroll
    for (int j = 0; j < 8; ++j) {
        hi.s[j] = f2bf(x[j]);
        lo.s[j] = f2bf(x[j] - bf2f(hi.s[j]));
    }
    unsigned short* base = out + (size_t)row * K3 + k;
    if (MODE_A) {
        *(short8*)&base[0]    = hi.v;
        *(short8*)&base[1024] = lo.v;
        *(short8*)&base[2048] = hi.v;
    } else {
        *(short8*)&base[0]    = hi.v;
        *(short8*)&base[1024] = hi.v;
        *(short8*)&base[2048] = lo.v;
    }
}

// ---------------------------------------------------------------------------
// bf16 MFMA GEMM (m97 structure): C[M,N] = A[M,K] @ B[N,K]^T, f32 out.
// 128x128 tile, BK=32, 256 threads = 4 waves (2x2), 64x64 per wave.
// ---------------------------------------------------------------------------
__device__ __forceinline__ void async_copy16(const void* g, const void* l) {
    __builtin_amdgcn_global_load_lds(
        (const __attribute__((address_space(1))) void*)(uintptr_t)g,
        (__attribute__((address_space(3))) void*)(uintptr_t)l, 16, 0, 0);
}

__global__ __launch_bounds__(256) void gemm_bf16(const unsigned short* __restrict__ A,
                                                 const unsigned short* __restrict__ B,
                                                 float* __restrict__ C,
                                                 int M, int N, int K) {
    __shared__ __align__(16) unsigned short As[128 * 32];
    __shared__ __align__(16) unsigned short Bs[128 * 32];

    const int tid = threadIdx.x;
    const int wave = tid >> 6;
    const int lane = tid & 63;
    const int wr = wave >> 1;
    const int wc = wave & 1;
    const int fr = lane & 15;
    const int fq = lane >> 4;

    const int bm = blockIdx.y * 128;
    const int bn = blockIdx.x * 128;

    const int srow = tid >> 2;
    const int sseg = (tid & 3) << 3;

    f32x4 acc[4][4];
#pragma unroll
    for (int i = 0; i < 4; ++i)
#pragma unroll
        for (int j = 0; j < 4; ++j) acc[i][j] = (f32x4)0.f;

    for (int k0 = 0; k0 < K; k0 += 32) {
#pragma unroll
        for (int c = 0; c < 2; ++c) {
            async_copy16(&A[(size_t)(bm + c * 64 + srow) * K + k0 + sseg],
                         &As[(c * 256 + wave * 64) * 8]);
            async_copy16(&B[(size_t)(bn + c * 64 + srow) * K + k0 + sseg],
                         &Bs[(c * 256 + wave * 64) * 8]);
        }
        __syncthreads();

        short8 a[4], b[4];
#pragma unroll
        for (int i = 0; i < 4; ++i)
            a[i] = *(const short8*)&As[(wr * 64 + i * 16 + fr) * 32 + fq * 8];
#pragma unroll
        for (int j = 0; j < 4; ++j)
            b[j] = *(const short8*)&Bs[(wc * 64 + j * 16 + fr) * 32 + fq * 8];
#pragma unroll
        for (int i = 0; i < 4; ++i)
#pragma unroll
            for (int j = 0; j < 4; ++j)
                acc[i][j] = __builtin_amdgcn_mfma_f32_16x16x32_bf16(a[i], b[j], acc[i][j], 0, 0, 0);
        __syncthreads();
    }

#pragma unroll
    for (int i = 0; i < 4; ++i)
#pragma unroll
        for (int j = 0; j < 4; ++j) {
            int col = bn + wc * 64 + j * 16 + fr;
#pragma unroll
            for (int r = 0; r < 4; ++r) {
                int row = bm + wr * 64 + i * 16 + fq * 4 + r;
                C[(size_t)row * N + col] = acc[i][j][r];
            }
        }
}

// ---------------------------------------------------------------------------
// Feature map from fused qkv buffer: qkv[T][1536], q at col0=0, k at col0=256.
// ---------------------------------------------------------------------------
__global__ __launch_bounds__(256) void feat_kernel(const float* __restrict__ qkv,
                                                   int col0,
                                                   const float* __restrict__ gamma,
                                                   const float* __restrict__ beta,
                                                   float* __restrict__ phi) {
    int p = blockIdx.x * blockDim.x + threadIdx.x;
    int h = p >> 10;
    int t = p & 1023;

    float x[16];
    float mu = 0.f;
#pragma unroll
    for (int f = 0; f < 16; ++f) {
        x[f] = qkv[(size_t)t * QKV_N + col0 + h * FEAT + f];
        mu += x[f];
    }
    mu *= (1.f / 16.f);
    float var = 0.f;
#pragma unroll
    for (int f = 0; f < 16; ++f) {
        float d = x[f] - mu;
        var += d * d;
    }
    var *= (1.f / 16.f);
    float rstd = rsqrtf(var + 1e-5f);

    float xn[16];
#pragma unroll
    for (int f = 0; f < 16; ++f)
        xn[f] = (x[f] - mu) * rstd * gamma[f] + beta[f];

    float* outp = phi + ((size_t)(h << 10) + t) * NFEAT;
    const float c1 = 0.25f;
    const float c2 = 0.35355339059327373f;
#pragma unroll
    for (int f = 0; f < 16; ++f) outp[f] = xn[f] * xn[f] * c1;
    int idx = 16;
#pragma unroll
    for (int i = 0; i < 16; ++i)
#pragma unroll
        for (int j = i + 1; j < 16; ++j) outp[idx++] = xn[i] * xn[j] * c2;
}

// ---------------------------------------------------------------------------
// Phase 1: per-chunk KV outer-product sums and K-feature sums.
// ---------------------------------------------------------------------------
__global__ __launch_bounds__(256) void chunk_kv(const float* __restrict__ phi_k,
                                                const float* __restrict__ qkv,
                                                float* __restrict__ KV,
                                                float* __restrict__ Z) {
    const int c = blockIdx.x;
    const int h = blockIdx.y;
    const int tid = threadIdx.x;
    __shared__ float pk_s[CL * NFEAT];
    __shared__ float v_s[CL * HD];

    const float* pk_g = phi_k + ((size_t)(h * T_LEN + c * CL)) * NFEAT;
    for (int idx = tid; idx < CL * NFEAT; idx += 256) pk_s[idx] = pk_g[idx];
    for (int idx = tid; idx < CL * HD; idx += 256) {
        int t = idx >> 6, d = idx & 63;
        v_s[idx] = qkv[(size_t)(c * CL + t) * QKV_N + 512 + h * HD + d];
    }
    __syncthreads();

    const int d = tid & 63;
    const int fg = tid >> 6;
    float* kv_out = KV + ((size_t)(h * NC + c)) * SSTATE;
    float* z_out = Z + ((size_t)(h * NC + c)) * NFEAT;
    for (int n = 0; n < 34; ++n) {
        int f = fg * 34 + n;
        float acc = 0.f;
        float zacc = 0.f;
#pragma unroll
        for (int t = 0; t < CL; ++t) {
            float pk = pk_s[t * NFEAT + f];
            acc += pk * v_s[t * HD + d];
            zacc += pk;
        }
        kv_out[f * HD + d] = acc;
        if (d == 0) z_out[f] = zacc;
    }
}

// ---------------------------------------------------------------------------
// Phase 2: exclusive prefix scan over chunks (per head).
// ---------------------------------------------------------------------------
__global__ __launch_bounds__(256) void chunk_scan(float* __restrict__ KV,
                                                  float* __restrict__ Z) {
    const int bx = blockIdx.x;
    const int h = blockIdx.y;
    const int tid = threadIdx.x;
    if (bx < 34) {
        int e = bx * 256 + tid;
        float run = 0.f;
        float* base = KV + (size_t)h * NC * SSTATE + e;
        for (int c = 0; c < NC; ++c) {
            float val = base[(size_t)c * SSTATE];
            base[(size_t)c * SSTATE] = run;
            run += val;
        }
    } else if (tid < NFEAT) {
        float run = 0.f;
        float* base = Z + (size_t)h * NC * NFEAT + tid;
        for (int c = 0; c < NC; ++c) {
            float val = base[(size_t)c * NFEAT];
            base[(size_t)c * NFEAT] = run;
            run += val;
        }
    }
}

// ---------------------------------------------------------------------------
// Phase 3: per-chunk output.
// ---------------------------------------------------------------------------
__global__ __launch_bounds__(256) void chunk_out(const float* __restrict__ phi_q,
                                                 const float* __restrict__ phi_k,
                                                 const float* __restrict__ qkv,
                                                 const float* __restrict__ KV,
                                                 const float* __restrict__ Z,
                                                 float* __restrict__ y) {
    const int c = blockIdx.x;
    const int h = blockIdx.y;
    const int tid = threadIdx.x;

    __shared__ float pq_s[CL * 137];
    __shared__ float pk_s[CL * 137];
    __shared__ float A_s[CL * CL];
    __shared__ float v_s[CL * HD];

    const float* pq_g = phi_q + ((size_t)(h * T_LEN + c * CL)) * NFEAT;
    const float* pk_g = phi_k + ((size_t)(h * T_LEN + c * CL)) * NFEAT;
    for (int idx = tid; idx < CL * NFEAT; idx += 256) {
        int t = idx / NFEAT;
        pq_s[idx + t] = pq_g[idx];
        pk_s[idx + t] = pk_g[idx];
    }
    for (int idx = tid; idx < CL * HD; idx += 256) {
        int t = idx >> 6, d = idx & 63;
        v_s[idx] = qkv[(size_t)(c * CL + t) * QKV_N + 512 + h * HD + d];
    }
    __syncthreads();

    for (int e = tid; e < CL * CL; e += 256) {
        int t = e >> 5, s = e & 31;
        float acc = 0.f;
        if (s <= t) {
#pragma unroll 8
            for (int f = 0; f < NFEAT; ++f)
                acc += pq_s[t * 137 + f] * pk_s[s * 137 + f];
        }
        A_s[e] = acc;
    }
    __syncthreads();

    const int d = tid & 63;
    const int tg = tid >> 6;
    const float* kv_pref = KV + ((size_t)(h * NC + c)) * SSTATE;
    const float* z_pref = Z + ((size_t)(h * NC + c)) * NFEAT;

    float num[8], den[8];
#pragma unroll
    for (int i = 0; i < 8; ++i) { num[i] = 0.f; den[i] = 0.f; }

    for (int f = 0; f < NFEAT; ++f) {
        float sp = kv_pref[f * HD + d];
        float zp = z_pref[f];
#pragma unroll
        for (int i = 0; i < 8; ++i) {
            float pq = pq_s[(tg * 8 + i) * 137 + f];
            num[i] += pq * sp;
            den[i] += pq * zp;
        }
    }
#pragma unroll
    for (int s = 0; s < CL; ++s) {
        float vv = v_s[s * HD + d];
#pragma unroll
        for (int i = 0; i < 8; ++i) {
            float a = A_s[(tg * 8 + i) * CL + s];
            num[i] += a * vv;
            den[i] += a;
        }
    }
#pragma unroll
    for (int i = 0; i < 8; ++i) {
        int t = c * CL + tg * 8 + i;
        y[(size_t)t * (HEADS * HD) + h * HD + d] = num[i] / (den[i] + 1e-5f);
    }
}

extern "C" void kernel_launch(void* const* d_in, const int* in_sizes, int n_in,
                              void* d_out, int out_size, void* d_ws, size_t ws_size,
                              hipStream_t stream) {
    const float* hs    = (const float*)d_in[0];
    const float* Wq    = (const float*)d_in[1];
    const float* Wk    = (const float*)d_in[2];
    const float* Wv    = (const float*)d_in[3];
    const float* Wo    = (const float*)d_in[4];
    const float* gamma = (const float*)d_in[5];
    const float* beta  = (const float*)d_in[6];
    float* out = (float*)d_out;

    float* ws = (float*)d_ws;
    float* qkv   = ws;                                   // 1024*1536
    float* phi_q = qkv + 1024 * QKV_N;                   // 16*1024*136
    float* phi_k = phi_q + HEADS * T_LEN * NFEAT;
    float* y     = phi_k + HEADS * T_LEN * NFEAT;        // 1024*1024
    float* KV    = y + 1024 * 1024;                      // 16*32*8704
    float* Z     = KV + (size_t)HEADS * NC * SSTATE;     // 16*32*136
    unsigned short* hs3   = (unsigned short*)(Z + HEADS * NC * NFEAT);  // 1024*3072
    unsigned short* wqkv3 = hs3 + (size_t)1024 * K3;     // 1536*3072
    unsigned short* wo_b  = wqkv3 + (size_t)QKV_N * K3;  // 1024*1024
    unsigned short* y_b   = wo_b + (size_t)1024 * 1024;  // 1024*1024

    dim3 blk(256);
    // split-convert activations (A-layout) and weights (B-layout)
    cvt_split<1><<<512, blk, 0, stream>>>(hs, hs3, 1024 * 1024);
    cvt_split<0><<<128, blk, 0, stream>>>(Wq, wqkv3, 256 * 1024);
    cvt_split<0><<<128, blk, 0, stream>>>(Wk, wqkv3 + (size_t)256 * K3, 256 * 1024);
    cvt_split<0><<<512, blk, 0, stream>>>(Wv, wqkv3 + (size_t)512 * K3, 1024 * 1024);
    cvt_bf16<<<512, blk, 0, stream>>>(Wo, wo_b, 1024 * 1024);

    // fused QKV projection, fp32-faithful: [1024,1536] = hs3 @ wqkv3^T (K=3072)
    gemm_bf16<<<dim3(QKV_N / 128, 1024 / 128), blk, 0, stream>>>(hs3, wqkv3, qkv,
                                                                 1024, QKV_N, K3);

    feat_kernel<<<64, blk, 0, stream>>>(qkv, 0, gamma, beta, phi_q);
    feat_kernel<<<64, blk, 0, stream>>>(qkv, 256, gamma, beta, phi_k);

    chunk_kv<<<dim3(NC, HEADS), blk, 0, stream>>>(phi_k, qkv, KV, Z);
    chunk_scan<<<dim3(35, HEADS), blk, 0, stream>>>(KV, Z);
    chunk_out<<<dim3(NC, HEADS), blk, 0, stream>>>(phi_q, phi_k, qkv, KV, Z, y);

    // out = y @ Wo^T, plain bf16 (error here is linear & small)
    cvt_bf16<<<512, blk, 0, stream>>>(y, y_b, 1024 * 1024);
    gemm_bf16<<<dim3(1024 / 128, 1024 / 128), blk, 0, stream>>>(y_b, wo_b, out,
                                                                1024, 1024, 1024);
}

// Round 5
// 113.323 us; speedup vs baseline: 10.9220x; 1.6520x over previous
//
#include <hip/hip_runtime.h>
#include <hip/hip_bf16.h>

#define HID 1024
#define HEADS 16
#define FEAT 16
#define HD 64
#define T_LEN 1024
#define NFEAT 136   // 16 diag + 120 off-diag
#define CL 32       // chunk length
#define NC 32       // chunks per head
#define SSTATE (NFEAT * HD)  // 8704

typedef __attribute__((ext_vector_type(8))) short short8;
typedef __attribute__((ext_vector_type(4))) float f32x4;

// ---------------------------------------------------------------------------
// f32 <-> bf16 helpers
// ---------------------------------------------------------------------------
__device__ __forceinline__ unsigned short f2bf(float f) {
    union { float f; unsigned int u; } x;
    x.f = f;
    unsigned int u = x.u;
    unsigned int r = u + 0x7fffu + ((u >> 16) & 1u);
    return (unsigned short)(r >> 16);
}
__device__ __forceinline__ float bf2f(unsigned short s) {
    union { unsigned int u; float f; } x;
    x.u = ((unsigned int)s) << 16;
    return x.f;
}

// ---------------------------------------------------------------------------
// Fused conversion kernel. Block ranges:
//   [0,512)    hs  -> hs3  [1024][3072] split-A  [hi | lo | hi]
//   [512,640)  Wq  -> wqk3 rows 0..255  split-B  [hi | hi | lo]
//   [640,768)  Wk  -> wqk3 rows 256..511 split-B
//   [768,1280) Wv  -> wv_b [1024][1024] plain bf16
//   [1280,1792) Wo -> wo_b [1024][1024] plain bf16
// ---------------------------------------------------------------------------
__device__ __forceinline__ void split_store(const float* __restrict__ in,
                                            unsigned short* __restrict__ out,
                                            int i, int rowoff, int a_mode) {
    float4 a = *(const float4*)&in[i];
    float4 b = *(const float4*)&in[i + 4];
    float x[8] = {a.x, a.y, a.z, a.w, b.x, b.y, b.z, b.w};
    union { unsigned short s[8]; short8 v; } hi, lo;
#pragma unroll
    for (int j = 0; j < 8; ++j) {
        hi.s[j] = f2bf(x[j]);
        lo.s[j] = f2bf(x[j] - bf2f(hi.s[j]));
    }
    unsigned short* base = out + (size_t)((i >> 10) + rowoff) * 3072 + (i & 1023);
    if (a_mode) {
        *(short8*)&base[0]    = hi.v;
        *(short8*)&base[1024] = lo.v;
        *(short8*)&base[2048] = hi.v;
    } else {
        *(short8*)&base[0]    = hi.v;
        *(short8*)&base[1024] = hi.v;
        *(short8*)&base[2048] = lo.v;
    }
}

__device__ __forceinline__ void plain_store(const float* __restrict__ in,
                                            unsigned short* __restrict__ out, int i) {
    float4 a = *(const float4*)&in[i];
    float4 b = *(const float4*)&in[i + 4];
    union { unsigned short s[8]; short8 v; } o;
    o.s[0] = f2bf(a.x); o.s[1] = f2bf(a.y); o.s[2] = f2bf(a.z); o.s[3] = f2bf(a.w);
    o.s[4] = f2bf(b.x); o.s[5] = f2bf(b.y); o.s[6] = f2bf(b.z); o.s[7] = f2bf(b.w);
    *(short8*)&out[i] = o.v;
}

__global__ __launch_bounds__(256) void cvt_all(const float* __restrict__ hs,
                                               const float* __restrict__ Wq,
                                               const float* __restrict__ Wk,
                                               const float* __restrict__ Wv,
                                               const float* __restrict__ Wo,
                                               unsigned short* __restrict__ hs3,
                                               unsigned short* __restrict__ wqk3,
                                               unsigned short* __restrict__ wv_b,
                                               unsigned short* __restrict__ wo_b) {
    int bx = blockIdx.x;
    int tid = threadIdx.x;
    if (bx < 512) {
        split_store(hs, hs3, (bx * 256 + tid) * 8, 0, 1);
    } else if (bx < 640) {
        split_store(Wq, wqk3, ((bx - 512) * 256 + tid) * 8, 0, 0);
    } else if (bx < 768) {
        split_store(Wk, wqk3, ((bx - 640) * 256 + tid) * 8, 256, 0);
    } else if (bx < 1280) {
        plain_store(Wv, wv_b, ((bx - 768) * 256 + tid) * 8);
    } else {
        plain_store(Wo, wo_b, ((bx - 1280) * 256 + tid) * 8);
    }
}

// ---------------------------------------------------------------------------
// Depth-2 pipelined bf16 MFMA GEMM core. 128x128 tile, BK=32, 256 threads
// (4 waves 2x2, 64x64/wave). 3 LDS buffers; stage(it+2) issued at iter it;
// end-of-iter fused "vmcnt(4) lgkmcnt(0); s_barrier" keeps the newest stage
// in flight across the barrier (counted-vmcnt, T4) while guaranteeing all
// ds_reads drained before any wave's next-stage DMA overwrites LDS.
// ---------------------------------------------------------------------------
__device__ __forceinline__ void async_copy16(const void* g, const void* l) {
    __builtin_amdgcn_global_load_lds(
        (const __attribute__((address_space(1))) void*)(uintptr_t)g,
        (__attribute__((address_space(3))) void*)(uintptr_t)l, 16, 0, 0);
}

#define PIPE_SYNC_KEEP4() asm volatile("s_waitcnt vmcnt(4) lgkmcnt(0)\n\ts_barrier" ::: "memory")
#define PIPE_SYNC_DRAIN() asm volatile("s_waitcnt vmcnt(0) lgkmcnt(0)\n\ts_barrier" ::: "memory")

__device__ __forceinline__ void gemm_pipe(const unsigned short* __restrict__ A,
                                          const unsigned short* __restrict__ B,
                                          float* __restrict__ C,
                                          int lda, int ldb, int ldc,
                                          int bm, int bn, int ntiles,
                                          unsigned short (&As)[3][4096],
                                          unsigned short (&Bs)[3][4096]) {
    const int tid = threadIdx.x;
    const int wave = tid >> 6;
    const int lane = tid & 63;
    const int wr = wave >> 1;
    const int wc = wave & 1;
    const int fr = lane & 15;
    const int fq = lane >> 4;
    const int srow = tid >> 2;
    const int sseg = (tid & 3) << 3;

    f32x4 acc[4][4];
#pragma unroll
    for (int i = 0; i < 4; ++i)
#pragma unroll
        for (int j = 0; j < 4; ++j) acc[i][j] = (f32x4)0.f;

    auto stage = [&](int buf, int tile) {
        const int k0 = tile << 5;
#pragma unroll
        for (int c = 0; c < 2; ++c) {
            async_copy16(&A[(size_t)(bm + c * 64 + srow) * lda + k0 + sseg],
                         &As[buf][(c * 256 + wave * 64) * 8]);
            async_copy16(&B[(size_t)(bn + c * 64 + srow) * ldb + k0 + sseg],
                         &Bs[buf][(c * 256 + wave * 64) * 8]);
        }
    };
    auto compute = [&](int buf) {
        short8 a[4], b[4];
#pragma unroll
        for (int i = 0; i < 4; ++i)
            a[i] = *(const short8*)&As[buf][(wr * 64 + i * 16 + fr) * 32 + fq * 8];
#pragma unroll
        for (int j = 0; j < 4; ++j)
            b[j] = *(const short8*)&Bs[buf][(wc * 64 + j * 16 + fr) * 32 + fq * 8];
#pragma unroll
        for (int i = 0; i < 4; ++i)
#pragma unroll
            for (int j = 0; j < 4; ++j)
                acc[i][j] = __builtin_amdgcn_mfma_f32_16x16x32_bf16(a[i], b[j], acc[i][j], 0, 0, 0);
    };

    stage(0, 0);
    stage(1, 1);
    PIPE_SYNC_KEEP4();  // tile 0 landed; tile 1 may still fly
    for (int it = 0; it < ntiles - 2; ++it) {
        stage((it + 2) % 3, it + 2);
        compute(it % 3);
        PIPE_SYNC_KEEP4();  // oldest stage (tile it+1) landed
    }
    compute((ntiles - 2) % 3);
    PIPE_SYNC_DRAIN();      // last stage landed
    compute((ntiles - 1) % 3);

#pragma unroll
    for (int i = 0; i < 4; ++i)
#pragma unroll
        for (int j = 0; j < 4; ++j) {
            int col = bn + wc * 64 + j * 16 + fr;
#pragma unroll
            for (int r = 0; r < 4; ++r) {
                int row = bm + wr * 64 + i * 16 + fq * 4 + r;
                C[(size_t)row * ldc + col] = acc[i][j][r];
            }
        }
}

// ---------------------------------------------------------------------------
// Grouped QKV GEMM, 160 blocks x 32 K-iters:
//  bx<96 : qk split-K partial seg=bx/32 : C_seg = A_seg @ B_seg^T  [1024x512]
//  bx>=96: v = hs_hi @ Wv_hi^T                                     [1024x1024]
// ---------------------------------------------------------------------------
__global__ __launch_bounds__(256) void gemm_qkv(const unsigned short* __restrict__ hs3,
                                                const unsigned short* __restrict__ wqk3,
                                                const unsigned short* __restrict__ wv_b,
                                                float* __restrict__ qk_part,
                                                float* __restrict__ v_f) {
    __shared__ __align__(16) unsigned short As[3][4096];
    __shared__ __align__(16) unsigned short Bs[3][4096];
    const int bx = blockIdx.x;
    const unsigned short *A, *B;
    float* C;
    int lda, ldb, ldc, bm, bn;
    if (bx < 96) {
        int seg = bx >> 5, r = bx & 31;
        bm = (r >> 2) * 128; bn = (r & 3) * 128;
        A = hs3 + seg * 1024;  lda = 3072;
        B = wqk3 + seg * 1024; ldb = 3072;
        C = qk_part + (size_t)seg * (1024 * 512); ldc = 512;
    } else {
        int r = bx - 96;
        bm = (r >> 3) * 128; bn = (r & 7) * 128;
        A = hs3;  lda = 3072;
        B = wv_b; ldb = 1024;
        C = v_f;  ldc = 1024;
    }
    gemm_pipe(A, B, C, lda, ldb, ldc, bm, bn, 32, As, Bs);
}

// ---------------------------------------------------------------------------
// Wo GEMM, split-K=2: 128 blocks x 16 K-iters -> out_part[2][1024][1024]
// ---------------------------------------------------------------------------
__global__ __launch_bounds__(256) void gemm_wo(const unsigned short* __restrict__ y_b,
                                               const unsigned short* __restrict__ wo_b,
                                               float* __restrict__ out_part) {
    __shared__ __align__(16) unsigned short As[3][4096];
    __shared__ __align__(16) unsigned short Bs[3][4096];
    const int bx = blockIdx.x;
    const int seg = bx >> 6;
    const int r = bx & 63;
    const int bm = (r >> 3) * 128, bn = (r & 7) * 128;
    gemm_pipe(y_b + seg * 512, wo_b + seg * 512,
              out_part + (size_t)seg * (1024 * 1024),
              1024, 1024, 1024, bm, bn, 16, As, Bs);
}

__global__ __launch_bounds__(256) void reduce_out(const float* __restrict__ out_part,
                                                  float* __restrict__ out) {
    int i = (blockIdx.x * 256 + threadIdx.x) * 8;
    float4 a0 = *(const float4*)&out_part[i];
    float4 a1 = *(const float4*)&out_part[i + 4];
    float4 b0 = *(const float4*)&out_part[i + 1048576];
    float4 b1 = *(const float4*)&out_part[i + 1048576 + 4];
    float4 o0 = make_float4(a0.x + b0.x, a0.y + b0.y, a0.z + b0.z, a0.w + b0.w);
    float4 o1 = make_float4(a1.x + b1.x, a1.y + b1.y, a1.z + b1.z, a1.w + b1.w);
    *(float4*)&out[i] = o0;
    *(float4*)&out[i + 4] = o1;
}

// ---------------------------------------------------------------------------
// Feature map: sums the 3 qk split-K partials, then LN(16) + 136 features.
// qk_part: [3][1024][512]; q at col0=0, k at col0=256. phi: [HEADS][T][136]
// ---------------------------------------------------------------------------
__global__ __launch_bounds__(256) void feat_kernel(const float* __restrict__ qk_part,
                                                   int col0,
                                                   const float* __restrict__ gamma,
                                                   const float* __restrict__ beta,
                                                   float* __restrict__ phi) {
    int p = blockIdx.x * blockDim.x + threadIdx.x;
    int h = p >> 10;
    int t = p & 1023;

    const float* base = qk_part + (size_t)t * 512 + col0 + h * FEAT;
    float x[16];
    float mu = 0.f;
#pragma unroll
    for (int f = 0; f < 16; ++f) {
        x[f] = base[f] + base[f + 524288] + base[f + 1048576];
        mu += x[f];
    }
    mu *= (1.f / 16.f);
    float var = 0.f;
#pragma unroll
    for (int f = 0; f < 16; ++f) {
        float d = x[f] - mu;
        var += d * d;
    }
    var *= (1.f / 16.f);
    float rstd = rsqrtf(var + 1e-5f);

    float xn[16];
#pragma unroll
    for (int f = 0; f < 16; ++f)
        xn[f] = (x[f] - mu) * rstd * gamma[f] + beta[f];

    float* outp = phi + ((size_t)(h << 10) + t) * NFEAT;
    const float c1 = 0.25f;
    const float c2 = 0.35355339059327373f;
#pragma unroll
    for (int f = 0; f < 16; ++f) outp[f] = xn[f] * xn[f] * c1;
    int idx = 16;
#pragma unroll
    for (int i = 0; i < 16; ++i)
#pragma unroll
        for (int j = i + 1; j < 16; ++j) outp[idx++] = xn[i] * xn[j] * c2;
}

// ---------------------------------------------------------------------------
// Phase 1: per-chunk KV outer-product sums and K-feature sums.
// v_f: [1024][1024] (col = h*64+d)
// ---------------------------------------------------------------------------
__global__ __launch_bounds__(256) void chunk_kv(const float* __restrict__ phi_k,
                                                const float* __restrict__ v_f,
                                                float* __restrict__ KV,
                                                float* __restrict__ Z) {
    const int c = blockIdx.x;
    const int h = blockIdx.y;
    const int tid = threadIdx.x;
    __shared__ float pk_s[CL * NFEAT];
    __shared__ float v_s[CL * HD];

    const float* pk_g = phi_k + ((size_t)(h * T_LEN + c * CL)) * NFEAT;
    for (int idx = tid; idx < CL * NFEAT; idx += 256) pk_s[idx] = pk_g[idx];
    for (int idx = tid; idx < CL * HD; idx += 256) {
        int t = idx >> 6, d = idx & 63;
        v_s[idx] = v_f[(size_t)(c * CL + t) * 1024 + h * HD + d];
    }
    __syncthreads();

    const int d = tid & 63;
    const int fg = tid >> 6;
    float* kv_out = KV + ((size_t)(h * NC + c)) * SSTATE;
    float* z_out = Z + ((size_t)(h * NC + c)) * NFEAT;
    for (int n = 0; n < 34; ++n) {
        int f = fg * 34 + n;
        float acc = 0.f;
        float zacc = 0.f;
#pragma unroll
        for (int t = 0; t < CL; ++t) {
            float pk = pk_s[t * NFEAT + f];
            acc += pk * v_s[t * HD + d];
            zacc += pk;
        }
        kv_out[f * HD + d] = acc;
        if (d == 0) z_out[f] = zacc;
    }
}

// ---------------------------------------------------------------------------
// Phase 2: exclusive prefix scan over chunks (per head).
// ---------------------------------------------------------------------------
__global__ __launch_bounds__(256) void chunk_scan(float* __restrict__ KV,
                                                  float* __restrict__ Z) {
    const int bx = blockIdx.x;
    const int h = blockIdx.y;
    const int tid = threadIdx.x;
    if (bx < 34) {
        int e = bx * 256 + tid;
        float run = 0.f;
        float* base = KV + (size_t)h * NC * SSTATE + e;
        for (int c = 0; c < NC; ++c) {
            float val = base[(size_t)c * SSTATE];
            base[(size_t)c * SSTATE] = run;
            run += val;
        }
    } else if (tid < NFEAT) {
        float run = 0.f;
        float* base = Z + (size_t)h * NC * NFEAT + tid;
        for (int c = 0; c < NC; ++c) {
            float val = base[(size_t)c * NFEAT];
            base[(size_t)c * NFEAT] = run;
            run += val;
        }
    }
}

// ---------------------------------------------------------------------------
// Phase 3: per-chunk output; writes y directly as bf16.
// ---------------------------------------------------------------------------
__global__ __launch_bounds__(256) void chunk_out(const float* __restrict__ phi_q,
                                                 const float* __restrict__ phi_k,
                                                 const float* __restrict__ v_f,
                                                 const float* __restrict__ KV,
                                                 const float* __restrict__ Z,
                                                 unsigned short* __restrict__ y_b) {
    const int c = blockIdx.x;
    const int h = blockIdx.y;
    const int tid = threadIdx.x;

    __shared__ float pq_s[CL * 137];
    __shared__ float pk_s[CL * 137];
    __shared__ float A_s[CL * CL];
    __shared__ float v_s[CL * HD];

    const float* pq_g = phi_q + ((size_t)(h * T_LEN + c * CL)) * NFEAT;
    const float* pk_g = phi_k + ((size_t)(h * T_LEN + c * CL)) * NFEAT;
    for (int idx = tid; idx < CL * NFEAT; idx += 256) {
        int t = idx / NFEAT;
        pq_s[idx + t] = pq_g[idx];
        pk_s[idx + t] = pk_g[idx];
    }
    for (int idx = tid; idx < CL * HD; idx += 256) {
        int t = idx >> 6, d = idx & 63;
        v_s[idx] = v_f[(size_t)(c * CL + t) * 1024 + h * HD + d];
    }
    __syncthreads();

    for (int e = tid; e < CL * CL; e += 256) {
        int t = e >> 5, s = e & 31;
        float acc = 0.f;
        if (s <= t) {
#pragma unroll 8
            for (int f = 0; f < NFEAT; ++f)
                acc += pq_s[t * 137 + f] * pk_s[s * 137 + f];
        }
        A_s[e] = acc;
    }
    __syncthreads();

    const int d = tid & 63;
    const int tg = tid >> 6;
    const float* kv_pref = KV + ((size_t)(h * NC + c)) * SSTATE;
    const float* z_pref = Z + ((size_t)(h * NC + c)) * NFEAT;

    float num[8], den[8];
#pragma unroll
    for (int i = 0; i < 8; ++i) { num[i] = 0.f; den[i] = 0.f; }

    for (int f = 0; f < NFEAT; ++f) {
        float sp = kv_pref[f * HD + d];
        float zp = z_pref[f];
#pragma unroll
        for (int i = 0; i < 8; ++i) {
            float pq = pq_s[(tg * 8 + i) * 137 + f];
            num[i] += pq * sp;
            den[i] += pq * zp;
        }
    }
#pragma unroll
    for (int s = 0; s < CL; ++s) {
        float vv = v_s[s * HD + d];
#pragma unroll
        for (int i = 0; i < 8; ++i) {
            float a = A_s[(tg * 8 + i) * CL + s];
            num[i] += a * vv;
            den[i] += a;
        }
    }
#pragma unroll
    for (int i = 0; i < 8; ++i) {
        int t = c * CL + tg * 8 + i;
        y_b[(size_t)t * 1024 + h * HD + d] = f2bf(num[i] / (den[i] + 1e-5f));
    }
}

extern "C" void kernel_launch(void* const* d_in, const int* in_sizes, int n_in,
                              void* d_out, int out_size, void* d_ws, size_t ws_size,
                              hipStream_t stream) {
    const float* hs    = (const float*)d_in[0];
    const float* Wq    = (const float*)d_in[1];
    const float* Wk    = (const float*)d_in[2];
    const float* Wv    = (const float*)d_in[3];
    const float* Wo    = (const float*)d_in[4];
    const float* gamma = (const float*)d_in[5];
    const float* beta  = (const float*)d_in[6];
    float* out = (float*)d_out;

    float* ws = (float*)d_ws;
    float* qk_part = ws;                                  // 3*1024*512
    float* v_f     = qk_part + 3 * 1024 * 512;            // 1024*1024
    float* phi_q   = v_f + 1024 * 1024;                   // 16*1024*136
    float* phi_k   = phi_q + HEADS * T_LEN * NFEAT;
    float* KV      = phi_k + HEADS * T_LEN * NFEAT;       // 16*32*8704
    float* Z       = KV + (size_t)HEADS * NC * SSTATE;    // 16*32*136
    float* out_part = Z + HEADS * NC * NFEAT;             // 2*1024*1024
    unsigned short* hs3  = (unsigned short*)(out_part + 2 * 1024 * 1024);  // 1024*3072
    unsigned short* wqk3 = hs3 + (size_t)1024 * 3072;     // 512*3072
    unsigned short* wv_b = wqk3 + (size_t)512 * 3072;     // 1024*1024
    unsigned short* wo_b = wv_b + (size_t)1024 * 1024;    // 1024*1024
    unsigned short* y_b  = wo_b + (size_t)1024 * 1024;    // 1024*1024

    dim3 blk(256);
    cvt_all<<<1792, blk, 0, stream>>>(hs, Wq, Wk, Wv, Wo, hs3, wqk3, wv_b, wo_b);

    gemm_qkv<<<160, blk, 0, stream>>>(hs3, wqk3, wv_b, qk_part, v_f);

    feat_kernel<<<64, blk, 0, stream>>>(qk_part, 0, gamma, beta, phi_q);
    feat_kernel<<<64, blk, 0, stream>>>(qk_part, 256, gamma, beta, phi_k);

    chunk_kv<<<dim3(NC, HEADS), blk, 0, stream>>>(phi_k, v_f, KV, Z);
    chunk_scan<<<dim3(35, HEADS), blk, 0, stream>>>(KV, Z);
    chunk_out<<<dim3(NC, HEADS), blk, 0, stream>>>(phi_q, phi_k, v_f, KV, Z, y_b);

    gemm_wo<<<128, blk, 0, stream>>>(y_b, wo_b, out_part);
    reduce_out<<<512, blk, 0, stream>>>(out_part, out);
}